// Round 9
// baseline (635.714 us; speedup 1.0000x reference)
//
#include <hip/hip_runtime.h>
#include <math.h>

// Problem constants (reference: B=4, T=4096, D_MODEL=128, N_HEADS=4, HEAD_DIM=32)
#define B_   4
#define T_   4096
#define DM_  128
#define NH_  4
#define HD_  32
#define TOKENS (B_ * T_)               // 16384

typedef __attribute__((ext_vector_type(8))) short short8;   // 8 bf16 = 4 VGPRs (MFMA A/B frag)
typedef __attribute__((ext_vector_type(4))) float floatx4;  // MFMA C/D frag

__device__ __forceinline__ unsigned short f2bf(float f) {
    union { float f; unsigned int u; } v; v.f = f;
    unsigned int u = v.u;
    u += 0x7fffu + ((u >> 16) & 1u);   // round-to-nearest-even
    return (unsigned short)(u >> 16);
}
__device__ __forceinline__ void split_bf(float v, unsigned short& hi, unsigned short& lo) {
    unsigned short h = f2bf(v);
    float hf = __uint_as_float(((unsigned int)h) << 16);
    hi = h;
    lo = f2bf(v - hf);
}

#define LROW 136   // bf16 LDS tile row stride: 128 + 8 pad shorts = 272 B (17*16B)

// Device-scope grid barrier.  Safe because ALL 1024 blocks are co-resident
// by construction: LDS 34816 B -> 4 blocks/CU, launch_bounds(256,4) -> VGPR<=128,
// 16 waves/CU <= 32.  Release fence + agent-scope atomic arrive; acquire-load
// spin (no RMW contention); acquire fence invalidates CU L1 / XCD L2 (G16).
__device__ __forceinline__ void grid_barrier(unsigned* c, unsigned target) {
    __syncthreads();
    if (threadIdx.x == 0) {
        __threadfence();                                   // release (writeback)
        __hip_atomic_fetch_add(c, 1u, __ATOMIC_RELEASE, __HIP_MEMORY_SCOPE_AGENT);
        while (__hip_atomic_load(c, __ATOMIC_ACQUIRE, __HIP_MEMORY_SCOPE_AGENT) < target)
            __builtin_amdgcn_s_sleep(8);
        __threadfence();                                   // acquire (invalidate)
    }
    __syncthreads();
}

// -------------------------------------------------------------------------
// Fused single-dispatch pipeline (1024 blocks x 256 thr, manual barriers):
//   Phase A: QKV projection (R5 structure) — 1536 tasks strided over grid.
//   Phase B: bf16 MFMA causal flash attention (R5 structure, 71 us known).
//   Phase C: output projection (R5 structure) — 512 tasks on blocks 0..511.
// LDS: one 34816 B arena, aliased per phase (4 blocks/CU co-resident).
// -------------------------------------------------------------------------
__global__ __launch_bounds__(256, 4) void fused_kernel(
    const float* __restrict__ x, const float* __restrict__ Wqkv,
    const float* __restrict__ Wout,
    unsigned short* __restrict__ q_bf, unsigned short* __restrict__ k_bf,
    unsigned short* __restrict__ v_t, float* __restrict__ att,
    float* __restrict__ out, unsigned* __restrict__ bar)
{
    __shared__ __align__(16) char smem[34816];

    const int tid  = threadIdx.x;
    const int wave = tid >> 6, lane = tid & 63;
    const int m    = lane & 15, q4 = lane >> 4;
    const int bid  = blockIdx.x;

    // =====================================================================
    // Phase A: QKV projection.  C = x·W^T (Q,K chunks) / C^T = W·x^T (V).
    // Outputs: Q bf16 PRE-SCALED by log2(e)/sqrt(32); K bf16; V^T (bh,32,t).
    // =====================================================================
    {
        unsigned short* whi = (unsigned short*)smem;
        unsigned short* wlo = whi + 64 * LROW;
        const float scale = 0.2550052509571414f;      // log2(e)/sqrt(32)

        for (int task = bid; task < 1536; task += 1024) {
            const int m0 = (task & 255) * 64;
            const int ch = task >> 8;                 // 0..5

            // x frags direct from global: row m0+wave*16+m (A or B operand)
            short8 Ah[4], Al[4];
            {
                const float4* xg = (const float4*)(x + (size_t)(m0 + wave * 16 + m) * DM_);
                #pragma unroll
                for (int ks = 0; ks < 4; ++ks) {
                    float4 a = xg[ks * 8 + q4 * 2];
                    float4 b = xg[ks * 8 + q4 * 2 + 1];
                    ushort4 h0, l0, h1, l1;
                    split_bf(a.x, h0.x, l0.x); split_bf(a.y, h0.y, l0.y);
                    split_bf(a.z, h0.z, l0.z); split_bf(a.w, h0.w, l0.w);
                    split_bf(b.x, h1.x, l1.x); split_bf(b.y, h1.y, l1.y);
                    split_bf(b.z, h1.z, l1.z); split_bf(b.w, h1.w, l1.w);
                    Ah[ks] = short8{(short)h0.x, (short)h0.y, (short)h0.z, (short)h0.w,
                                    (short)h1.x, (short)h1.y, (short)h1.z, (short)h1.w};
                    Al[ks] = short8{(short)l0.x, (short)l0.y, (short)l0.z, (short)l0.w,
                                    (short)l1.x, (short)l1.y, (short)l1.z, (short)l1.w};
                }
            }

            __syncthreads();   // prior task's LDS reads complete
            {   // stage W chunk (rows ch*64..+63) -> hi/lo bf16 LDS
                const float4* wg = (const float4*)(Wqkv + (size_t)ch * 64 * DM_);
                #pragma unroll
                for (int i = 0; i < 8; ++i) {
                    const int f = tid + 256 * i;
                    float4 v = wg[f];
                    const int row = f >> 5, k4 = f & 31;
                    ushort4 h, l;
                    split_bf(v.x, h.x, l.x); split_bf(v.y, h.y, l.y);
                    split_bf(v.z, h.z, l.z); split_bf(v.w, h.w, l.w);
                    *(ushort4*)(whi + row * LROW + k4 * 4) = h;
                    *(ushort4*)(wlo + row * LROW + k4 * 4) = l;
                }
            }
            __syncthreads();

            const int b    = m0 >> 12;
            const int tloc = (m0 & (T_ - 1)) + wave * 16;

            if (ch < 4) {   // Q (ch 0,1) and K (ch 2,3): C = x·W^T
                #pragma unroll
                for (int nb = 0; nb < 4; ++nb) {
                    floatx4 acc = {0.f, 0.f, 0.f, 0.f};
                    #pragma unroll
                    for (int ks = 0; ks < 4; ++ks) {
                        short8 Bh = *(const short8*)(whi + (nb * 16 + m) * LROW + ks * 32 + q4 * 8);
                        short8 Bl = *(const short8*)(wlo + (nb * 16 + m) * LROW + ks * 32 + q4 * 8);
                        acc = __builtin_amdgcn_mfma_f32_16x16x32_bf16(Ah[ks], Bh, acc, 0, 0, 0);
                        acc = __builtin_amdgcn_mfma_f32_16x16x32_bf16(Ah[ks], Bl, acc, 0, 0, 0);
                        acc = __builtin_amdgcn_mfma_f32_16x16x32_bf16(Al[ks], Bh, acc, 0, 0, 0);
                    }
                    const int n  = ch * 64 + nb * 16 + m;   // col = lane m
                    const int hh = (n >> 5) & 3;
                    const int d  = n & 31;
                    const int bh = b * NH_ + hh;
                    const int t0 = tloc + q4 * 4;           // row = q4*4+reg
                    if (ch < 2) {
                        #pragma unroll
                        for (int reg = 0; reg < 4; ++reg)
                            q_bf[((size_t)bh * T_ + t0 + reg) * HD_ + d] = f2bf(acc[reg] * scale);
                    } else {
                        #pragma unroll
                        for (int reg = 0; reg < 4; ++reg)
                            k_bf[((size_t)bh * T_ + t0 + reg) * HD_ + d] = f2bf(acc[reg]);
                    }
                }
            } else {        // V (ch 4,5): C^T = W·x^T — rows = W n-idx, cols = tokens
                #pragma unroll
                for (int nb = 0; nb < 4; ++nb) {
                    floatx4 acc = {0.f, 0.f, 0.f, 0.f};
                    #pragma unroll
                    for (int ks = 0; ks < 4; ++ks) {
                        short8 Bh = *(const short8*)(whi + (nb * 16 + m) * LROW + ks * 32 + q4 * 8);
                        short8 Bl = *(const short8*)(wlo + (nb * 16 + m) * LROW + ks * 32 + q4 * 8);
                        acc = __builtin_amdgcn_mfma_f32_16x16x32_bf16(Bh, Ah[ks], acc, 0, 0, 0);
                        acc = __builtin_amdgcn_mfma_f32_16x16x32_bf16(Bh, Al[ks], acc, 0, 0, 0);
                        acc = __builtin_amdgcn_mfma_f32_16x16x32_bf16(Bl, Ah[ks], acc, 0, 0, 0);
                    }
                    const int t = tloc + m;                 // col = token (lane m)
                    #pragma unroll
                    for (int reg = 0; reg < 4; ++reg) {     // row = n local = q4*4+reg
                        const int n  = ch * 64 + nb * 16 + q4 * 4 + reg;
                        const int hh = (n >> 5) & 3;
                        const int d  = n & 31;
                        v_t[((size_t)(b * NH_ + hh) * HD_ + d) * T_ + t] = f2bf(acc[reg]);
                    }
                }
            }
        }
    }

    grid_barrier(bar, 1024);

    // =====================================================================
    // Phase B: causal flash attention (S^T = K·Q^T formulation, R5 exact).
    // =====================================================================
    {
        char* kLds = smem;             // 64 rows x 80 B  (K tile, (t,d))
        char* vLds = smem + 5120;      // 32 rows x 144 B (V^T tile, (d,t))
        char* pT   = smem + 9728 + wave * 2304;   // wave-private P^T 16x144 B

        // Dispatch swizzle: XCD-locality (2 heads/XCD) + per-CU qt balance.
        const int pid = bid;
        const int xcd = pid & 7;
        const int r_  = pid >> 3;
        const int bh  = xcd * 2 + (r_ & 1);
        const int j_  = r_ >> 1;
        const int a_  = j_ & 15, k_ = j_ >> 4;
        const int qt  = (k_ == 0) ? a_ : (k_ == 1) ? 63 - a_
                      : (k_ == 2) ? 32 + a_ : 31 - a_;

        const size_t qkbase = (size_t)bh * T_ * HD_;
        const char* kg = (const char*)(k_bf + qkbase);
        const char* vg = (const char*)(v_t + qkbase);

        short8 qf = *(const short8*)((const char*)(q_bf + qkbase)
                     + (size_t)(qt * 64 + wave * 16 + m) * 64 + q4 * 16);
        const int qrow = wave * 16 + m;        // query row within the 64-block

        floatx4 O0 = {0.f, 0.f, 0.f, 0.f}, O1 = {0.f, 0.f, 0.f, 0.f};
        float mx = -INFINITY, ls = 0.f;

        for (int kt = 0; kt <= qt; ++kt) {
            __syncthreads();
            {   // stage K tile (64x64B) + V^T tile (32x128B), over 256 thr
                const int krow = tid >> 2, ku = tid & 3;
                short8 kv = *(const short8*)(kg + (size_t)(kt * 64 + krow) * 64 + ku * 16);
                const int vd = tid >> 3, vu = tid & 7;
                short8 vv = *(const short8*)(vg + (size_t)vd * (T_ * 2)
                                                + (size_t)kt * 128 + vu * 16);
                *(short8*)(kLds + krow * 80 + ku * 16) = kv;
                *(short8*)(vLds + vd * 144 + vu * 16) = vv;
            }
            __syncthreads();

            // S^T = K·Q^T : C[s=q4*4+reg][q=m]
            floatx4 st[4];
            #pragma unroll
            for (int sb = 0; sb < 4; ++sb) {
                short8 kfrag = *(const short8*)(kLds + (sb * 16 + m) * 80 + q4 * 16);
                floatx4 z = {0.f, 0.f, 0.f, 0.f};
                st[sb] = __builtin_amdgcn_mfma_f32_16x16x32_bf16(kfrag, qf, z, 0, 0, 0);
            }

            if (kt == qt) {   // causal: mask s_local > qrow
                #pragma unroll
                for (int sb = 0; sb < 4; ++sb)
                    #pragma unroll
                    for (int reg = 0; reg < 4; ++reg)
                        if (sb * 16 + q4 * 4 + reg > qrow) st[sb][reg] = -INFINITY;
            }

            float rmax = -INFINITY;
            #pragma unroll
            for (int sb = 0; sb < 4; ++sb)
                #pragma unroll
                for (int reg = 0; reg < 4; ++reg) rmax = fmaxf(rmax, st[sb][reg]);
            rmax = fmaxf(rmax, __shfl_xor(rmax, 16, 64));
            rmax = fmaxf(rmax, __shfl_xor(rmax, 32, 64));

            const float mn = fmaxf(mx, rmax);
            const float alpha = __builtin_amdgcn_exp2f(mx - mn);   // 0 on first tile
            mx = mn;

            float psum = 0.f;
            #pragma unroll
            for (int sb = 0; sb < 4; ++sb) {
                float p0 = __builtin_amdgcn_exp2f(st[sb][0] - mn);
                float p1 = __builtin_amdgcn_exp2f(st[sb][1] - mn);
                float p2 = __builtin_amdgcn_exp2f(st[sb][2] - mn);
                float p3 = __builtin_amdgcn_exp2f(st[sb][3] - mn);
                psum += (p0 + p1) + (p2 + p3);
                unsigned u0 = __float_as_uint(p0) + 0x8000u;
                unsigned u1 = __float_as_uint(p1) + 0x8000u;
                unsigned u2 = __float_as_uint(p2) + 0x8000u;
                unsigned u3 = __float_as_uint(p3) + 0x8000u;
                uint2 pk;
                pk.x = __builtin_amdgcn_perm(u1, u0, 0x07060302);
                pk.y = __builtin_amdgcn_perm(u3, u2, 0x07060302);
                *(uint2*)(pT + m * 144 + sb * 32 + q4 * 8) = pk;
            }
            psum += __shfl_xor(psum, 16, 64);
            psum += __shfl_xor(psum, 32, 64);
            ls = ls * alpha + psum;
            #pragma unroll
            for (int reg = 0; reg < 4; ++reg) { O0[reg] *= alpha; O1[reg] *= alpha; }

            // drain wave-internal P^T writes before cross-lane B-frag reads
            __asm__ volatile("s_waitcnt lgkmcnt(0)" ::: "memory");

            short8 b0  = *(const short8*)(pT + m * 144 + q4 * 16);
            short8 b1  = *(const short8*)(pT + m * 144 + 64 + q4 * 16);
            short8 v00 = *(const short8*)(vLds + m * 144 + q4 * 16);
            short8 v10 = *(const short8*)(vLds + m * 144 + 64 + q4 * 16);
            short8 v01 = *(const short8*)(vLds + (16 + m) * 144 + q4 * 16);
            short8 v11 = *(const short8*)(vLds + (16 + m) * 144 + 64 + q4 * 16);
            O0 = __builtin_amdgcn_mfma_f32_16x16x32_bf16(v00, b0, O0, 0, 0, 0);
            O0 = __builtin_amdgcn_mfma_f32_16x16x32_bf16(v10, b1, O0, 0, 0, 0);
            O1 = __builtin_amdgcn_mfma_f32_16x16x32_bf16(v01, b0, O1, 0, 0, 0);
            O1 = __builtin_amdgcn_mfma_f32_16x16x32_bf16(v11, b1, O1, 0, 0, 0);
        }

        // epilogue: O^T[d][q=m]; write fp32 att, layout (B,T,H,D)
        const float inv = 1.f / ls;
        const int b = bh >> 2, h = bh & 3;
        const int t = qt * 64 + qrow;
        float* orow = att + (((size_t)b * T_ + t) * NH_ + h) * HD_;
        *(float4*)(orow + q4 * 4)      = make_float4(O0[0] * inv, O0[1] * inv,
                                                     O0[2] * inv, O0[3] * inv);
        *(float4*)(orow + 16 + q4 * 4) = make_float4(O1[0] * inv, O1[1] * inv,
                                                     O1[2] * inv, O1[3] * inv);
    }

    grid_barrier(bar + 16, 1024);   // separate cache line

    // =====================================================================
    // Phase C: output projection (R5 structure) — blocks 0..511.
    // =====================================================================
    if (bid < 512) {
        unsigned short* whi = (unsigned short*)smem;
        unsigned short* wlo = whi + 64 * LROW;
        const int m0 = (bid & 255) * 64;
        const int ch = bid >> 8;                  // 0..1

        short8 Ah[4], Al[4];
        {
            const float4* xg = (const float4*)(att + (size_t)(m0 + wave * 16 + m) * DM_);
            #pragma unroll
            for (int ks = 0; ks < 4; ++ks) {
                float4 av = xg[ks * 8 + q4 * 2];
                float4 bv = xg[ks * 8 + q4 * 2 + 1];
                ushort4 h0, l0, h1, l1;
                split_bf(av.x, h0.x, l0.x); split_bf(av.y, h0.y, l0.y);
                split_bf(av.z, h0.z, l0.z); split_bf(av.w, h0.w, l0.w);
                split_bf(bv.x, h1.x, l1.x); split_bf(bv.y, h1.y, l1.y);
                split_bf(bv.z, h1.z, l1.z); split_bf(bv.w, h1.w, l1.w);
                Ah[ks] = short8{(short)h0.x, (short)h0.y, (short)h0.z, (short)h0.w,
                                (short)h1.x, (short)h1.y, (short)h1.z, (short)h1.w};
                Al[ks] = short8{(short)l0.x, (short)l0.y, (short)l0.z, (short)l0.w,
                                (short)l1.x, (short)l1.y, (short)l1.z, (short)l1.w};
            }
        }

        __syncthreads();   // phase B smem reads done
        {   // stage Wout chunk (rows ch*64..+63) -> hi/lo bf16 LDS
            const float4* wg = (const float4*)(Wout + (size_t)ch * 64 * DM_);
            #pragma unroll
            for (int i = 0; i < 8; ++i) {
                const int f = tid + 256 * i;
                float4 v = wg[f];
                const int row = f >> 5, k4 = f & 31;
                ushort4 h, l;
                split_bf(v.x, h.x, l.x); split_bf(v.y, h.y, l.y);
                split_bf(v.z, h.z, l.z); split_bf(v.w, h.w, l.w);
                *(ushort4*)(whi + row * LROW + k4 * 4) = h;
                *(ushort4*)(wlo + row * LROW + k4 * 4) = l;
            }
        }
        __syncthreads();

        #pragma unroll
        for (int nb = 0; nb < 4; ++nb) {
            floatx4 acc = {0.f, 0.f, 0.f, 0.f};
            #pragma unroll
            for (int ks = 0; ks < 4; ++ks) {
                short8 Bh = *(const short8*)(whi + (nb * 16 + m) * LROW + ks * 32 + q4 * 8);
                short8 Bl = *(const short8*)(wlo + (nb * 16 + m) * LROW + ks * 32 + q4 * 8);
                acc = __builtin_amdgcn_mfma_f32_16x16x32_bf16(Ah[ks], Bh, acc, 0, 0, 0);
                acc = __builtin_amdgcn_mfma_f32_16x16x32_bf16(Ah[ks], Bl, acc, 0, 0, 0);
                acc = __builtin_amdgcn_mfma_f32_16x16x32_bf16(Al[ks], Bh, acc, 0, 0, 0);
            }
            const int n = ch * 64 + nb * 16 + m;
            const int tok0 = m0 + wave * 16 + q4 * 4;
            #pragma unroll
            for (int reg = 0; reg < 4; ++reg)
                out[(size_t)(tok0 + reg) * DM_ + n] = acc[reg];
        }
    }
}

// -------------------------------------------------------------------------
extern "C" void kernel_launch(void* const* d_in, const int* in_sizes, int n_in,
                              void* d_out, int out_size, void* d_ws, size_t ws_size,
                              hipStream_t stream) {
    const float* x    = (const float*)d_in[0];   // (4,4096,128) fp32
    const float* Wqkv = (const float*)d_in[1];   // (384,128)    fp32
    const float* Wout = (const float*)d_in[2];   // (128,128)    fp32
    float* out = (float*)d_out;                  // (4,4096,128) fp32

    // ws layout (bytes): q_bf 4MB | k_bf 4MB | v_t 4MB | att fp32 8MB | barriers
    char* ws = (char*)d_ws;
    const size_t MB = 1024 * 1024;
    unsigned short* q_bf = (unsigned short*)(ws);
    unsigned short* k_bf = (unsigned short*)(ws + 4 * MB);
    unsigned short* v_t  = (unsigned short*)(ws + 8 * MB);
    float*          att  = (float*)(ws + 12 * MB);
    unsigned*       bar  = (unsigned*)(ws + 20 * MB);

    hipMemsetAsync(bar, 0, 256, stream);   // zero barrier counters every call
    fused_kernel<<<1024, 256, 0, stream>>>(x, Wqkv, Wout, q_bf, k_bf, v_t,
                                           att, out, bar);
}

// Round 10
// 196.288 us; speedup vs baseline: 3.2387x; 3.2387x over previous
//
#include <hip/hip_runtime.h>
#include <math.h>

// Problem constants (reference: B=4, T=4096, D_MODEL=128, N_HEADS=4, HEAD_DIM=32)
#define B_   4
#define T_   4096
#define DM_  128
#define NH_  4
#define HD_  32
#define TOKENS (B_ * T_)               // 16384

typedef __attribute__((ext_vector_type(8))) short short8;   // 8 bf16 = 4 VGPRs (MFMA A/B frag)
typedef __attribute__((ext_vector_type(4))) float floatx4;  // MFMA C/D frag

__device__ __forceinline__ unsigned short f2bf(float f) {
    union { float f; unsigned int u; } v; v.f = f;
    unsigned int u = v.u;
    u += 0x7fffu + ((u >> 16) & 1u);   // round-to-nearest-even
    return (unsigned short)(u >> 16);
}
__device__ __forceinline__ void split_bf(float v, unsigned short& hi, unsigned short& lo) {
    unsigned short h = f2bf(v);
    float hf = __uint_as_float(((unsigned int)h) << 16);
    hi = h;
    lo = f2bf(v - hf);
}

#define LROW 136   // bf16 LDS tile row stride: 128 + 8 pad shorts = 272 B (17*16B)

// -------------------------------------------------------------------------
// Kernel 1: K/V projection via MFMA (R5 structure, Q branch removed) + each
// block zeroes its 8 KB slice of `out` (stream-ordered before attn atomics).
// grid (256, 4): ch = blockIdx.y + 2  (K: ch 2,3 ; V: ch 4,5).
// K bf16 (bh,t,32); V^T bf16 (bh,32,t).
// -------------------------------------------------------------------------
__global__ __launch_bounds__(256) void kv_proj_kernel(
    const float* __restrict__ x, const float* __restrict__ Wqkv,
    unsigned short* __restrict__ k_bf, unsigned short* __restrict__ v_t,
    float* __restrict__ out)
{
    __shared__ __align__(16) unsigned short whi[64 * LROW];   // 17 KB
    __shared__ __align__(16) unsigned short wlo[64 * LROW];   // 17 KB

    const int tid  = threadIdx.x;
    const int wave = tid >> 6, lane = tid & 63;
    const int m    = lane & 15, q4 = lane >> 4;
    const int m0   = blockIdx.x * 64;
    const int ch   = blockIdx.y + 2;              // 2..5

    {   // zero this block's slice of out: 2048 floats = 512 float4
        const int bid = blockIdx.y * 256 + blockIdx.x;          // 0..1023
        float4* oz = (float4*)(out + (size_t)bid * 2048);
        oz[tid]       = make_float4(0.f, 0.f, 0.f, 0.f);
        oz[tid + 256] = make_float4(0.f, 0.f, 0.f, 0.f);
    }

    {   // cooperative W chunk split: rows ch*64 .. +63
        const float4* wg = (const float4*)(Wqkv + (size_t)ch * 64 * DM_);
        #pragma unroll
        for (int i = 0; i < 8; ++i) {
            const int f = tid + 256 * i;
            float4 v = wg[f];
            const int row = f >> 5, k4 = f & 31;
            ushort4 h, l;
            split_bf(v.x, h.x, l.x); split_bf(v.y, h.y, l.y);
            split_bf(v.z, h.z, l.z); split_bf(v.w, h.w, l.w);
            *(ushort4*)(whi + row * LROW + k4 * 4) = h;
            *(ushort4*)(wlo + row * LROW + k4 * 4) = l;
        }
    }

    // x frags direct from global: row m0+wave*16+m (serves as A or B)
    short8 Ah[4], Al[4];
    {
        const float4* xg = (const float4*)(x + (size_t)(m0 + wave * 16 + m) * DM_);
        #pragma unroll
        for (int ks = 0; ks < 4; ++ks) {
            float4 a = xg[ks * 8 + q4 * 2];
            float4 b = xg[ks * 8 + q4 * 2 + 1];
            ushort4 h0, l0, h1, l1;
            split_bf(a.x, h0.x, l0.x); split_bf(a.y, h0.y, l0.y);
            split_bf(a.z, h0.z, l0.z); split_bf(a.w, h0.w, l0.w);
            split_bf(b.x, h1.x, l1.x); split_bf(b.y, h1.y, l1.y);
            split_bf(b.z, h1.z, l1.z); split_bf(b.w, h1.w, l1.w);
            Ah[ks] = short8{(short)h0.x, (short)h0.y, (short)h0.z, (short)h0.w,
                            (short)h1.x, (short)h1.y, (short)h1.z, (short)h1.w};
            Al[ks] = short8{(short)l0.x, (short)l0.y, (short)l0.z, (short)l0.w,
                            (short)l1.x, (short)l1.y, (short)l1.z, (short)l1.w};
        }
    }
    __syncthreads();

    const int b    = m0 >> 12;
    const int tloc = (m0 & (T_ - 1)) + wave * 16;

    if (ch < 4) {   // K (ch 2,3): C = x·W^T
        #pragma unroll
        for (int nb = 0; nb < 4; ++nb) {
            floatx4 acc = {0.f, 0.f, 0.f, 0.f};
            #pragma unroll
            for (int ks = 0; ks < 4; ++ks) {
                short8 Bh = *(const short8*)(whi + (nb * 16 + m) * LROW + ks * 32 + q4 * 8);
                short8 Bl = *(const short8*)(wlo + (nb * 16 + m) * LROW + ks * 32 + q4 * 8);
                acc = __builtin_amdgcn_mfma_f32_16x16x32_bf16(Ah[ks], Bh, acc, 0, 0, 0);
                acc = __builtin_amdgcn_mfma_f32_16x16x32_bf16(Ah[ks], Bl, acc, 0, 0, 0);
                acc = __builtin_amdgcn_mfma_f32_16x16x32_bf16(Al[ks], Bh, acc, 0, 0, 0);
            }
            const int n  = ch * 64 + nb * 16 + m;   // col = lane m
            const int hh = (n >> 5) & 3;
            const int d  = n & 31;
            const int bh = b * NH_ + hh;
            const int t0 = tloc + q4 * 4;           // row = q4*4+reg
            #pragma unroll
            for (int reg = 0; reg < 4; ++reg)
                k_bf[((size_t)bh * T_ + t0 + reg) * HD_ + d] = f2bf(acc[reg]);
        }
    } else {        // V (ch 4,5): C^T = W·x^T — rows = W n-idx, cols = tokens
        #pragma unroll
        for (int nb = 0; nb < 4; ++nb) {
            floatx4 acc = {0.f, 0.f, 0.f, 0.f};
            #pragma unroll
            for (int ks = 0; ks < 4; ++ks) {
                short8 Bh = *(const short8*)(whi + (nb * 16 + m) * LROW + ks * 32 + q4 * 8);
                short8 Bl = *(const short8*)(wlo + (nb * 16 + m) * LROW + ks * 32 + q4 * 8);
                acc = __builtin_amdgcn_mfma_f32_16x16x32_bf16(Bh, Ah[ks], acc, 0, 0, 0);
                acc = __builtin_amdgcn_mfma_f32_16x16x32_bf16(Bh, Al[ks], acc, 0, 0, 0);
                acc = __builtin_amdgcn_mfma_f32_16x16x32_bf16(Bl, Ah[ks], acc, 0, 0, 0);
            }
            const int t = tloc + m;                 // col = token (lane m)
            #pragma unroll
            for (int reg = 0; reg < 4; ++reg) {     // row = n local = q4*4+reg
                const int n  = ch * 64 + nb * 16 + q4 * 4 + reg;
                const int hh = (n >> 5) & 3;
                const int d  = n & 31;
                v_t[((size_t)(b * NH_ + hh) * HD_ + d) * T_ + t] = f2bf(acc[reg]);
            }
        }
    }
}

// -------------------------------------------------------------------------
// Kernel 2: fused attention = Q-projection prologue + R5 flash-attention
// loop (verbatim) + out-projection epilogue via fp32 atomicAdd.
// Prologue: Q(64x32) = x·Wq_h^T (hi/lo MFMA), scaled bf16 -> qLds -> B-frags.
// Epilogue: out_part^T(128n x 16q/wave) = Wout_h(hi/lo)·O^T(hi/lo),
//           32 atomic dword adds per lane onto zero-initialized out.
// -------------------------------------------------------------------------
__global__ __launch_bounds__(256, 4) void attn_mfma_kernel(
    const float* __restrict__ x, const float* __restrict__ Wqkv,
    const float* __restrict__ Wout,
    const unsigned short* __restrict__ kb, const unsigned short* __restrict__ vtb,
    float* __restrict__ out)
{
    __shared__ __align__(16) char smem[5120 + 4608 + 4 * 2304];   // 18.5 KB
    char* kLds = smem;             // 64 rows x 80 B  (K tile, (t,d)) ; qLds in prologue
    char* vLds = smem + 5120;      // 32 rows x 144 B (V^T tile, (d,t))
    const int tid  = threadIdx.x;
    const int wave = tid >> 6, lane = tid & 63;
    const int m    = lane & 15, q4 = lane >> 4;
    char* pT = smem + 9728 + wave * 2304;   // wave-private P^T: 16 q-rows x 144 B

    // Dispatch swizzle: XCD-locality (2 heads/XCD) + per-CU qt balance.
    const int pid = blockIdx.x;
    const int xcd = pid & 7;
    const int r_  = pid >> 3;
    const int bh  = xcd * 2 + (r_ & 1);
    const int j_  = r_ >> 1;
    const int a_  = j_ & 15, k_ = j_ >> 4;
    const int qt  = (k_ == 0) ? a_ : (k_ == 1) ? 63 - a_
                  : (k_ == 2) ? 32 + a_ : 31 - a_;

    const int b = bh >> 2, h = bh & 3;
    const size_t qkbase = (size_t)bh * T_ * HD_;
    const char* kg = (const char*)(kb + qkbase);
    const char* vg = (const char*)(vtb + qkbase);
    const float scale = 0.2550052509571414f;      // log2(e)/sqrt(32)

    // ---------- Prologue: Q tile (64 tokens x 32 d) = x·Wq_h^T ----------
    {
        // A-frags: x rows (token = qt*64 + wave*16 + m)
        short8 Ah[4], Al[4];
        const float4* xg = (const float4*)(x +
            (size_t)(b * T_ + qt * 64 + wave * 16 + m) * DM_);
        #pragma unroll
        for (int ks = 0; ks < 4; ++ks) {
            float4 a = xg[ks * 8 + q4 * 2];
            float4 bb = xg[ks * 8 + q4 * 2 + 1];
            ushort4 h0, l0, h1, l1;
            split_bf(a.x, h0.x, l0.x); split_bf(a.y, h0.y, l0.y);
            split_bf(a.z, h0.z, l0.z); split_bf(a.w, h0.w, l0.w);
            split_bf(bb.x, h1.x, l1.x); split_bf(bb.y, h1.y, l1.y);
            split_bf(bb.z, h1.z, l1.z); split_bf(bb.w, h1.w, l1.w);
            Ah[ks] = short8{(short)h0.x, (short)h0.y, (short)h0.z, (short)h0.w,
                            (short)h1.x, (short)h1.y, (short)h1.z, (short)h1.w};
            Al[ks] = short8{(short)l0.x, (short)l0.y, (short)l0.z, (short)l0.w,
                            (short)l1.x, (short)l1.y, (short)l1.z, (short)l1.w};
        }
        // B-frags: Wq rows n = h*32 + nb*16 + m (first 128 rows of Wqkv)
        #pragma unroll
        for (int nb = 0; nb < 2; ++nb) {
            floatx4 qacc = {0.f, 0.f, 0.f, 0.f};
            const float4* wq4 = (const float4*)(Wqkv +
                (size_t)(h * 32 + nb * 16 + m) * DM_);
            #pragma unroll
            for (int ks = 0; ks < 4; ++ks) {
                float4 a = wq4[ks * 8 + q4 * 2];
                float4 bb = wq4[ks * 8 + q4 * 2 + 1];
                ushort4 h0, l0, h1, l1;
                split_bf(a.x, h0.x, l0.x); split_bf(a.y, h0.y, l0.y);
                split_bf(a.z, h0.z, l0.z); split_bf(a.w, h0.w, l0.w);
                split_bf(bb.x, h1.x, l1.x); split_bf(bb.y, h1.y, l1.y);
                split_bf(bb.z, h1.z, l1.z); split_bf(bb.w, h1.w, l1.w);
                short8 Bh = short8{(short)h0.x, (short)h0.y, (short)h0.z, (short)h0.w,
                                   (short)h1.x, (short)h1.y, (short)h1.z, (short)h1.w};
                short8 Bl = short8{(short)l0.x, (short)l0.y, (short)l0.z, (short)l0.w,
                                   (short)l1.x, (short)l1.y, (short)l1.z, (short)l1.w};
                qacc = __builtin_amdgcn_mfma_f32_16x16x32_bf16(Ah[ks], Bh, qacc, 0, 0, 0);
                qacc = __builtin_amdgcn_mfma_f32_16x16x32_bf16(Ah[ks], Bl, qacc, 0, 0, 0);
                qacc = __builtin_amdgcn_mfma_f32_16x16x32_bf16(Al[ks], Bh, qacc, 0, 0, 0);
            }
            // C[token-local = q4*4+reg (within wave's 16)][d = nb*16+m]
            // -> qLds layout (q-row, d): row stride 80 B
            #pragma unroll
            for (int reg = 0; reg < 4; ++reg)
                *(unsigned short*)(kLds + (wave * 16 + q4 * 4 + reg) * 80
                                        + (nb * 16 + m) * 2) = f2bf(qacc[reg] * scale);
        }
    }
    __syncthreads();
    short8 qf = *(const short8*)(kLds + (wave * 16 + m) * 80 + q4 * 16);
    const int qrow = wave * 16 + m;        // query row within the 64-block

    floatx4 O0 = {0.f, 0.f, 0.f, 0.f}, O1 = {0.f, 0.f, 0.f, 0.f};
    float mx = -INFINITY, ls = 0.f;

    for (int kt = 0; kt <= qt; ++kt) {
        __syncthreads();
        {   // stage K tile (64x64B) + V^T tile (32x128B), over 256 thr
            const int krow = tid >> 2, ku = tid & 3;
            short8 kv = *(const short8*)(kg + (size_t)(kt * 64 + krow) * 64 + ku * 16);
            const int vd = tid >> 3, vu = tid & 7;
            short8 vv = *(const short8*)(vg + (size_t)vd * (T_ * 2)
                                            + (size_t)kt * 128 + vu * 16);
            *(short8*)(kLds + krow * 80 + ku * 16) = kv;
            *(short8*)(vLds + vd * 144 + vu * 16) = vv;
        }
        __syncthreads();

        // S^T = K·Q^T : C[s=q4*4+reg][q=m]
        floatx4 st[4];
        #pragma unroll
        for (int sb = 0; sb < 4; ++sb) {
            short8 kfrag = *(const short8*)(kLds + (sb * 16 + m) * 80 + q4 * 16);
            floatx4 z = {0.f, 0.f, 0.f, 0.f};
            st[sb] = __builtin_amdgcn_mfma_f32_16x16x32_bf16(kfrag, qf, z, 0, 0, 0);
        }

        if (kt == qt) {   // causal: mask s_local > qrow
            #pragma unroll
            for (int sb = 0; sb < 4; ++sb)
                #pragma unroll
                for (int reg = 0; reg < 4; ++reg)
                    if (sb * 16 + q4 * 4 + reg > qrow) st[sb][reg] = -INFINITY;
        }

        float rmax = -INFINITY;
        #pragma unroll
        for (int sb = 0; sb < 4; ++sb)
            #pragma unroll
            for (int reg = 0; reg < 4; ++reg) rmax = fmaxf(rmax, st[sb][reg]);
        rmax = fmaxf(rmax, __shfl_xor(rmax, 16, 64));
        rmax = fmaxf(rmax, __shfl_xor(rmax, 32, 64));

        const float mn = fmaxf(mx, rmax);
        const float alpha = __builtin_amdgcn_exp2f(mx - mn);   // 0 on first tile
        mx = mn;

        float psum = 0.f;
        #pragma unroll
        for (int sb = 0; sb < 4; ++sb) {
            float p0 = __builtin_amdgcn_exp2f(st[sb][0] - mn);
            float p1 = __builtin_amdgcn_exp2f(st[sb][1] - mn);
            float p2 = __builtin_amdgcn_exp2f(st[sb][2] - mn);
            float p3 = __builtin_amdgcn_exp2f(st[sb][3] - mn);
            psum += (p0 + p1) + (p2 + p3);
            unsigned u0 = __float_as_uint(p0) + 0x8000u;
            unsigned u1 = __float_as_uint(p1) + 0x8000u;
            unsigned u2 = __float_as_uint(p2) + 0x8000u;
            unsigned u3 = __float_as_uint(p3) + 0x8000u;
            uint2 pk;
            pk.x = __builtin_amdgcn_perm(u1, u0, 0x07060302);
            pk.y = __builtin_amdgcn_perm(u3, u2, 0x07060302);
            *(uint2*)(pT + m * 144 + sb * 32 + q4 * 8) = pk;
        }
        psum += __shfl_xor(psum, 16, 64);
        psum += __shfl_xor(psum, 32, 64);
        ls = ls * alpha + psum;
        #pragma unroll
        for (int reg = 0; reg < 4; ++reg) { O0[reg] *= alpha; O1[reg] *= alpha; }

        // drain wave-internal P^T writes before cross-lane B-frag reads
        __asm__ volatile("s_waitcnt lgkmcnt(0)" ::: "memory");

        short8 b0  = *(const short8*)(pT + m * 144 + q4 * 16);
        short8 b1  = *(const short8*)(pT + m * 144 + 64 + q4 * 16);
        short8 v00 = *(const short8*)(vLds + m * 144 + q4 * 16);
        short8 v10 = *(const short8*)(vLds + m * 144 + 64 + q4 * 16);
        short8 v01 = *(const short8*)(vLds + (16 + m) * 144 + q4 * 16);
        short8 v11 = *(const short8*)(vLds + (16 + m) * 144 + 64 + q4 * 16);
        O0 = __builtin_amdgcn_mfma_f32_16x16x32_bf16(v00, b0, O0, 0, 0, 0);
        O0 = __builtin_amdgcn_mfma_f32_16x16x32_bf16(v10, b1, O0, 0, 0, 0);
        O1 = __builtin_amdgcn_mfma_f32_16x16x32_bf16(v01, b0, O1, 0, 0, 0);
        O1 = __builtin_amdgcn_mfma_f32_16x16x32_bf16(v11, b1, O1, 0, 0, 0);
    }

    // ---------- Epilogue: out += O_h · Wout_h^T  via MFMA + atomics ----------
    const float inv = 1.f / ls;
    __syncthreads();   // all waves done with kLds/vLds/pT
    char* oLds = smem + wave * 2560;   // hi: 16 rows x 80 B ; lo at +1280

    // write O^T (normalized, hi/lo split) as (q,d) rows: lane holds
    // O^T[d = dblk*16 + q4*4 + reg][q = m] -> 4 consecutive d per reg -> b64
    {
        floatx4 Ox[2] = {O0, O1};
        #pragma unroll
        for (int dblk = 0; dblk < 2; ++dblk) {
            ushort4 hi4, lo4;
            split_bf(Ox[dblk][0] * inv, hi4.x, lo4.x);
            split_bf(Ox[dblk][1] * inv, hi4.y, lo4.y);
            split_bf(Ox[dblk][2] * inv, hi4.z, lo4.z);
            split_bf(Ox[dblk][3] * inv, hi4.w, lo4.w);
            uint2 ph, pl;
            ph.x = (unsigned)hi4.x | ((unsigned)hi4.y << 16);
            ph.y = (unsigned)hi4.z | ((unsigned)hi4.w << 16);
            pl.x = (unsigned)lo4.x | ((unsigned)lo4.y << 16);
            pl.y = (unsigned)lo4.z | ((unsigned)lo4.w << 16);
            *(uint2*)(oLds + m * 80 + dblk * 32 + q4 * 8)        = ph;
            *(uint2*)(oLds + 1280 + m * 80 + dblk * 32 + q4 * 8) = pl;
        }
    }
    __asm__ volatile("s_waitcnt lgkmcnt(0)" ::: "memory");   // wave-private

    short8 Bh = *(const short8*)(oLds + m * 80 + q4 * 16);          // O^T hi
    short8 Bl = *(const short8*)(oLds + 1280 + m * 80 + q4 * 16);   // O^T lo

    float* obase = out + (size_t)(b * T_ + qt * 64 + wave * 16 + m) * DM_;
    #pragma unroll
    for (int nb = 0; nb < 8; ++nb) {
        // A-frag: Wout row n = nb*16+m, cols h*32 + q4*8 .. +7 (hi/lo split)
        const float4* wo4 = (const float4*)(Wout + (size_t)(nb * 16 + m) * DM_ + h * 32);
        float4 a  = wo4[q4 * 2];
        float4 bb = wo4[q4 * 2 + 1];
        ushort4 h0, l0, h1, l1;
        split_bf(a.x, h0.x, l0.x); split_bf(a.y, h0.y, l0.y);
        split_bf(a.z, h0.z, l0.z); split_bf(a.w, h0.w, l0.w);
        split_bf(bb.x, h1.x, l1.x); split_bf(bb.y, h1.y, l1.y);
        split_bf(bb.z, h1.z, l1.z); split_bf(bb.w, h1.w, l1.w);
        short8 Awh = short8{(short)h0.x, (short)h0.y, (short)h0.z, (short)h0.w,
                            (short)h1.x, (short)h1.y, (short)h1.z, (short)h1.w};
        short8 Awl = short8{(short)l0.x, (short)l0.y, (short)l0.z, (short)l0.w,
                            (short)l1.x, (short)l1.y, (short)l1.z, (short)l1.w};
        floatx4 C = {0.f, 0.f, 0.f, 0.f};
        C = __builtin_amdgcn_mfma_f32_16x16x32_bf16(Awh, Bh, C, 0, 0, 0);
        C = __builtin_amdgcn_mfma_f32_16x16x32_bf16(Awh, Bl, C, 0, 0, 0);
        C = __builtin_amdgcn_mfma_f32_16x16x32_bf16(Awl, Bh, C, 0, 0, 0);
        // C[n-local = q4*4+reg][q = m] -> out[token][nb*16 + q4*4 + reg]
        #pragma unroll
        for (int reg = 0; reg < 4; ++reg)
            atomicAdd(obase + nb * 16 + q4 * 4 + reg, C[reg]);
    }
}

// -------------------------------------------------------------------------
extern "C" void kernel_launch(void* const* d_in, const int* in_sizes, int n_in,
                              void* d_out, int out_size, void* d_ws, size_t ws_size,
                              hipStream_t stream) {
    const float* x    = (const float*)d_in[0];   // (4,4096,128) fp32
    const float* Wqkv = (const float*)d_in[1];   // (384,128)    fp32
    const float* Wout = (const float*)d_in[2];   // (128,128)    fp32
    float* out = (float*)d_out;                  // (4,4096,128) fp32

    // ws layout (bytes): k_bf 4MB | v_t 4MB
    char* ws = (char*)d_ws;
    const size_t MB = 1024 * 1024;
    unsigned short* k_bf = (unsigned short*)(ws);
    unsigned short* v_t  = (unsigned short*)(ws + 4 * MB);

    kv_proj_kernel<<<dim3(256, 4), 256, 0, stream>>>(x, Wqkv, k_bf, v_t, out);
    attn_mfma_kernel<<<1024, 256, 0, stream>>>(x, Wqkv, Wout, k_bf, v_t, out);
}